// Round 1
// baseline (36004.196 us; speedup 1.0000x reference)
//
#include <hip/hip_runtime.h>
#include <stdint.h>

// Seq2Seq (bi-LSTM encoder + greedy LSTM decoder), MI355X gfx950.
// v1: all-fp32 persistent kernel. Correctness-first: greedy argmax feedback
// demands logits match the fp32 JAX reference to ~1e-6; bf16 MFMA would flip
// argmaxes. MFMA/bf16-screen optimizations deferred to later rounds.
//
// B=32 S=128 T=64 V=32000 E=512 H=512 (4H=2048 gates per cell)
//
// One kernel, 256 blocks x 1024 threads, 1 block/CU (147KB LDS), hand-rolled
// flag barrier (all blocks resident). Block bid owns 4 LSTM units of
// direction/cell d = bid>>7 (u0 = (bid&127)*4); c-state stays in registers of
// threads tid<128 across all 128 encoder + 63 decoder steps.

#define NT 1024
#define NBLK 256

constexpr int HSTR = 580;    // enc h-stage LDS row stride (512 + pad, %32==4)
constexpr int XSTR = 1156;   // dec [x|h]-stage stride (1024 + pad, %32==4)
constexpr unsigned LDS_BYTES = 150528;

// workspace layout (bytes)
constexpr size_t OFF_AMAX  = 0;                     // 63*32 u64 = 16128
constexpr size_t OFF_FLAGS = 16128;                 // 256 u32  = 1024
constexpr size_t OFF_XG    = 17408;                 // 256*128*32*16 f32 = 67108864
constexpr size_t OFF_HENC  = OFF_XG + 67108864ULL;  // 2buf*2dir*32*512 f32 = 262144
constexpr size_t OFF_HCAT  = OFF_HENC + 262144ULL;  // 2buf*32*1024 f32 = 262144
constexpr size_t WS_NEED   = OFF_HCAT + 262144ULL;  // ~67.7 MB

__device__ __forceinline__ float sigm(float x) {
  if (x >= 0.f) return 1.f / (1.f + expf(-x));
  float e = expf(x);
  return e / (1.f + e);
}

__device__ __forceinline__ void fma4(const float4& w, const float4& h, float4& a) {
  a.x = fmaf(w.x, h.x, a.x);
  a.y = fmaf(w.y, h.y, a.y);
  a.z = fmaf(w.z, h.z, a.z);
  a.w = fmaf(w.w, h.w, a.w);
}

__device__ __forceinline__ float hsum4(const float4& a) {
  return (a.x + a.y) + (a.z + a.w);
}

// device-scope flag barrier: 256 blocks, thread t<256 polls flags[t].
__device__ __forceinline__ void gbar(unsigned* flags, unsigned gen) {
  __syncthreads();
  if (threadIdx.x == 0) {
    __threadfence();
    __hip_atomic_store(&flags[blockIdx.x], gen, __ATOMIC_RELEASE,
                       __HIP_MEMORY_SCOPE_AGENT);
  }
  if (threadIdx.x < NBLK) {
    while (__hip_atomic_load(&flags[threadIdx.x], __ATOMIC_ACQUIRE,
                             __HIP_MEMORY_SCOPE_AGENT) < gen) {
      __builtin_amdgcn_s_sleep(2);
    }
  }
  __syncthreads();
}

__global__ __launch_bounds__(NT, 4) void s2s_kernel(
    const int* __restrict__ src, const int* __restrict__ tgt,
    const float* __restrict__ enc_emb, const float* __restrict__ dec_emb,
    const float* __restrict__ ewih_f, const float* __restrict__ ewhh_f,
    const float* __restrict__ ebih_f, const float* __restrict__ ebhh_f,
    const float* __restrict__ ewih_r, const float* __restrict__ ewhh_r,
    const float* __restrict__ ebih_r, const float* __restrict__ ebhh_r,
    const float* __restrict__ dwih_f, const float* __restrict__ dwhh_f,
    const float* __restrict__ dbih_f, const float* __restrict__ dbhh_f,
    const float* __restrict__ dwih_r, const float* __restrict__ dwhh_r,
    const float* __restrict__ dbih_r, const float* __restrict__ dbhh_r,
    const float* __restrict__ cls_w, const float* __restrict__ cls_b,
    float* __restrict__ out,
    unsigned long long* __restrict__ amax, unsigned* __restrict__ flags,
    float* __restrict__ Xg, float* __restrict__ h_enc, float* __restrict__ hcat) {
  extern __shared__ float smem[];
  const int tid = threadIdx.x;
  const int bid = blockIdx.x;
  const int d  = bid >> 7;          // 0 = forward, 1 = reverse
  const int u0 = (bid & 127) << 2;  // first of 4 owned LSTM units

  // LDS views per phase (aliased)
  float* hL  = smem;                      // enc: [32][HSTR]
  float* XgL = smem + 32 * HSTR;          // enc: [32*16]
  float* gL  = XgL + 512;                 // enc: [32*16]
  float* xhL = smem;                      // dec: [32][XSTR]
  float* gLd = smem + 32 * XSTR;          // dec: [32*16]
  float4* cT = (float4*)smem;             // cls: [256][33] float4

  // mapping E (phase0 + encoder scan): 2 rows x 4 b per thread, k-split 16
  const int rgE = tid >> 7;               // [0,8)
  const int bpE = (tid >> 4) & 7;         // [0,8)
  const int ksE = tid & 15;               // [0,16)
  const int r0E = rgE * 2, r1E = r0E + 1;
  const int growE0 = (r0E & 3) * 512 + u0 + (r0E >> 2);
  const int growE1 = (r1E & 3) * 512 + u0 + (r1E >> 2);
  // mapping D (decoder cells): 2 rows x 8 b per thread, k-split 32 over K=1024
  const int rgD = tid >> 7;
  const int bpD = (tid >> 5) & 3;         // [0,4)
  const int ksD = tid & 31;               // [0,32)
  const int r0D = rgD * 2, r1D = r0D + 1;
  const int growD0 = (r0D & 3) * 512 + u0 + (r0D >> 2);
  const int growD1 = (r1D & 3) * 512 + u0 + (r1D >> 2);

  const float* ewih = d ? ewih_r : ewih_f;
  const float* ewhh = d ? ewhh_r : ewhh_f;
  const float* ebih = d ? ebih_r : ebih_f;
  const float* ebhh = d ? ebhh_r : ebhh_f;
  const float* dwih = d ? dwih_r : dwih_f;
  const float* dwhh = d ? dwhh_r : dwhh_f;
  const float* dbih = d ? dbih_r : dbih_f;
  const float* dbhh = d ? dbhh_r : dbhh_f;

  float4 wA[8], wB[8];
  float biasA, biasB;
  float c_reg = 0.f;   // cell state for threads tid<128 (b=tid&31, j=tid>>5)
  unsigned gen = 0;

  // ---------------- phase 0: Xg = emb(src) @ wih^T + bih + bhh ----------------
#pragma unroll
  for (int i4 = 0; i4 < 8; ++i4) {
    wA[i4] = *(const float4*)(ewih + (size_t)growE0 * 512 + ksE * 32 + i4 * 4);
    wB[i4] = *(const float4*)(ewih + (size_t)growE1 * 512 + ksE * 32 + i4 * 4);
  }
  biasA = ebih[growE0] + ebhh[growE0];
  biasB = ebih[growE1] + ebhh[growE1];

  for (int t = 0; t < 128; ++t) {
    {  // stage x = enc_emb[src[b][t]] into hL
      int b = tid >> 5, i = tid & 31;
      int tok = src[b * 128 + t];
      const float* row = enc_emb + (size_t)tok * 512;
#pragma unroll
      for (int q = 0; q < 4; ++q) {
        int k = (i + 32 * q) * 4;
        float4 v = *(const float4*)(row + k);
        int pc = k + ((k >> 5) << 2);
        *(float4*)(hL + b * HSTR + pc) = v;
      }
    }
    __syncthreads();
    for (int gi = 0; gi < 4; ++gi) {
      int b = bpE * 4 + gi;
      const float* hb = hL + b * HSTR + ksE * 36;
      float4 a0 = {0, 0, 0, 0}, a1 = {0, 0, 0, 0};
#pragma unroll
      for (int i4 = 0; i4 < 8; ++i4) {
        float4 h4 = *(const float4*)(hb + i4 * 4);
        fma4(wA[i4], h4, a0);
        fma4(wB[i4], h4, a1);
      }
      float s0 = hsum4(a0), s1 = hsum4(a1);
#pragma unroll
      for (int m = 1; m <= 8; m <<= 1) {
        s0 += __shfl_xor(s0, m, 64);
        s1 += __shfl_xor(s1, m, 64);
      }
      if (ksE == 0) {
        float* xgp = Xg + ((size_t)bid << 16) + t * 512 + b * 16;
        xgp[r0E] = s0 + biasA;
        xgp[r1E] = s1 + biasB;
      }
    }
    __syncthreads();
  }

  // init h_enc[buf0] = 0 for owned units; zero out[:,0,:] slice
  if (tid < 128) {
    int b = tid & 31, j = tid >> 5;
    h_enc[((0 * 2 + d) * 32 + b) * 512 + u0 + j] = 0.f;
  }
  for (int i = tid; i < 4000; i += NT) {
    int b = i & 31, vv = i >> 5;  // vv < 125
    out[(size_t)b * 64 * 32000 + bid * 125 + vv] = 0.f;
  }
  gbar(flags, ++gen);

  // ---------------- encoder scan: 128 steps ----------------
#pragma unroll
  for (int i4 = 0; i4 < 8; ++i4) {
    wA[i4] = *(const float4*)(ewhh + (size_t)growE0 * 512 + ksE * 32 + i4 * 4);
    wB[i4] = *(const float4*)(ewhh + (size_t)growE1 * 512 + ksE * 32 + i4 * 4);
  }
  int cur = 0;
  for (int s = 0; s < 128; ++s) {
    const int td = d ? (127 - s) : s;
    {  // stage h_enc[cur][d] -> hL; stage this block's Xg slice -> XgL
      int b = tid >> 5, i = tid & 31;
      const float* hr = h_enc + ((size_t)(cur * 2 + d) * 32 + b) * 512;
#pragma unroll
      for (int q = 0; q < 4; ++q) {
        int k = (i + 32 * q) * 4;
        float4 v = *(const float4*)(hr + k);
        int pc = k + ((k >> 5) << 2);
        *(float4*)(hL + b * HSTR + pc) = v;
      }
      if (tid < 128) {
        ((float4*)XgL)[tid] =
            *(const float4*)(Xg + ((size_t)bid << 16) + td * 512 + tid * 4);
      }
    }
    __syncthreads();
    for (int gi = 0; gi < 4; ++gi) {
      int b = bpE * 4 + gi;
      const float* hb = hL + b * HSTR + ksE * 36;
      float4 a0 = {0, 0, 0, 0}, a1 = {0, 0, 0, 0};
#pragma unroll
      for (int i4 = 0; i4 < 8; ++i4) {
        float4 h4 = *(const float4*)(hb + i4 * 4);
        fma4(wA[i4], h4, a0);
        fma4(wB[i4], h4, a1);
      }
      float s0 = hsum4(a0), s1 = hsum4(a1);
#pragma unroll
      for (int m = 1; m <= 8; m <<= 1) {
        s0 += __shfl_xor(s0, m, 64);
        s1 += __shfl_xor(s1, m, 64);
      }
      if (ksE == 0) {
        gL[b * 16 + r0E] = s0 + XgL[b * 16 + r0E];
        gL[b * 16 + r1E] = s1 + XgL[b * 16 + r1E];
      }
    }
    __syncthreads();
    if (tid < 128) {
      int b = tid & 31, j = tid >> 5;
      float g_i = gL[b * 16 + (j << 2) + 0];
      float g_f = gL[b * 16 + (j << 2) + 1];
      float g_g = gL[b * 16 + (j << 2) + 2];
      float g_o = gL[b * 16 + (j << 2) + 3];
      c_reg = sigm(g_f) * c_reg + sigm(g_i) * tanhf(g_g);
      float h = sigm(g_o) * tanhf(c_reg);
      h_enc[(((cur ^ 1) * 2 + d) * 32 + b) * 512 + u0 + j] = h;
      if (s == 127) hcat[b * 1024 + d * 512 + u0 + j] = h;  // buf 0
    }
    gbar(flags, ++gen);
    cur ^= 1;
  }

  // ---------------- decoder: 63 steps ----------------
  {
    const float* s0p = (ksD < 16) ? (dwih + (size_t)growD0 * 512 + ksD * 32)
                                  : (dwhh + (size_t)growD0 * 512 + (ksD - 16) * 32);
    const float* s1p = (ksD < 16) ? (dwih + (size_t)growD1 * 512 + ksD * 32)
                                  : (dwhh + (size_t)growD1 * 512 + (ksD - 16) * 32);
#pragma unroll
    for (int i4 = 0; i4 < 8; ++i4) {
      wA[i4] = *(const float4*)(s0p + i4 * 4);
      wB[i4] = *(const float4*)(s1p + i4 * 4);
    }
    biasA = dbih[growD0] + dbhh[growD0];
    biasB = dbih[growD1] + dbhh[growD1];
  }

  for (int t = 0; t < 63; ++t) {
    const int p = t & 1;
    {  // stage [x | h_d] into xhL
      int b = tid >> 5, i = tid & 31;
      int tok;
      if (t == 0) {
        tok = tgt[b * 64];
      } else {
        unsigned long long kv = amax[(t - 1) * 32 + b];
        tok = (int)(0xFFFFFFFFu - (unsigned)(kv & 0xFFFFFFFFull));
      }
      const float* xr = dec_emb + (size_t)tok * 512;
      const float* hr = hcat + (size_t)p * 32768 + b * 1024 + d * 512;
#pragma unroll
      for (int q = 0; q < 4; ++q) {
        int k = (i + 32 * q) * 4;
        float4 v = *(const float4*)(xr + k);
        int pc = k + ((k >> 5) << 2);
        *(float4*)(xhL + b * XSTR + pc) = v;
      }
#pragma unroll
      for (int q = 0; q < 4; ++q) {
        int k = (i + 32 * q) * 4;
        float4 v = *(const float4*)(hr + k);
        int c2 = 512 + k;
        int pc = c2 + ((c2 >> 5) << 2);
        *(float4*)(xhL + b * XSTR + pc) = v;
      }
    }
    __syncthreads();
    for (int gi = 0; gi < 8; ++gi) {
      int b = bpD * 8 + gi;
      const float* hb = xhL + b * XSTR + ksD * 36;
      float4 a0 = {0, 0, 0, 0}, a1 = {0, 0, 0, 0};
#pragma unroll
      for (int i4 = 0; i4 < 8; ++i4) {
        float4 h4 = *(const float4*)(hb + i4 * 4);
        fma4(wA[i4], h4, a0);
        fma4(wB[i4], h4, a1);
      }
      float s0 = hsum4(a0), s1 = hsum4(a1);
#pragma unroll
      for (int m = 1; m <= 16; m <<= 1) {
        s0 += __shfl_xor(s0, m, 64);
        s1 += __shfl_xor(s1, m, 64);
      }
      if (ksD == 0) {
        gLd[b * 16 + r0D] = s0 + biasA;
        gLd[b * 16 + r1D] = s1 + biasB;
      }
    }
    __syncthreads();
    if (tid < 128) {
      int b = tid & 31, j = tid >> 5;
      float g_i = gLd[b * 16 + (j << 2) + 0];
      float g_f = gLd[b * 16 + (j << 2) + 1];
      float g_g = gLd[b * 16 + (j << 2) + 2];
      float g_o = gLd[b * 16 + (j << 2) + 3];
      c_reg = sigm(g_f) * c_reg + sigm(g_i) * tanhf(g_g);
      float h = sigm(g_o) * tanhf(c_reg);
      hcat[(size_t)(p ^ 1) * 32768 + b * 1024 + d * 512 + u0 + j] = h;
    }
    gbar(flags, ++gen);

    // ---- classifier: logits = hcat[p^1] @ cls_w^T + cls_b, argmax ----
    {
      int b = tid >> 5, kk = tid & 31;
      const float* hr = hcat + (size_t)(p ^ 1) * 32768 + b * 1024;
#pragma unroll
      for (int it = 0; it < 8; ++it) {
        int k4 = kk + it * 32;
        cT[k4 * 33 + b] = *(const float4*)(hr + k4 * 4);
      }
    }
    __syncthreads();
    if (tid < 512) {
      const int g8 = tid >> 5, cb = tid & 31;
      const int vbase = bid * 125 + g8 * 8;
      const int nrr = (g8 == 15) ? 5 : 8;
      float acc[8] = {0.f, 0.f, 0.f, 0.f, 0.f, 0.f, 0.f, 0.f};
      const float* wbase = cls_w + (size_t)vbase * 1024;
#pragma unroll 2
      for (int k4 = 0; k4 < 256; ++k4) {
        float4 h4 = cT[k4 * 33 + cb];
#pragma unroll
        for (int rr = 0; rr < 8; ++rr) {
          if (rr < nrr) {
            float4 w4 = *(const float4*)(wbase + (size_t)rr * 1024 + (k4 << 2));
            acc[rr] = fmaf(w4.x, h4.x,
                      fmaf(w4.y, h4.y,
                      fmaf(w4.z, h4.z,
                      fmaf(w4.w, h4.w, acc[rr]))));
          }
        }
      }
      unsigned long long bestkey = 0ull;
      float* orow = out + ((size_t)cb * 64 + (t + 1)) * 32000 + vbase;
#pragma unroll
      for (int rr = 0; rr < 8; ++rr) {
        if (rr < nrr) {
          float lg = acc[rr] + cls_b[vbase + rr];
          orow[rr] = lg;
          unsigned u = __float_as_uint(lg);
          u = (u & 0x80000000u) ? ~u : (u | 0x80000000u);
          unsigned long long key =
              ((unsigned long long)u << 32) | (0xFFFFFFFFu - (unsigned)(vbase + rr));
          bestkey = (key > bestkey) ? key : bestkey;
        }
      }
      atomicMax(&amax[t * 32 + cb], bestkey);
    }
    gbar(flags, ++gen);
  }
}

extern "C" void kernel_launch(void* const* d_in, const int* in_sizes, int n_in,
                              void* d_out, int out_size, void* d_ws, size_t ws_size,
                              hipStream_t stream) {
  (void)in_sizes; (void)n_in; (void)out_size; (void)ws_size;
  const int*   src     = (const int*)d_in[0];
  const int*   tgt     = (const int*)d_in[1];
  const float* enc_emb = (const float*)d_in[2];
  const float* dec_emb = (const float*)d_in[3];
  const float* ewih_f  = (const float*)d_in[4];
  const float* ewhh_f  = (const float*)d_in[5];
  const float* ebih_f  = (const float*)d_in[6];
  const float* ebhh_f  = (const float*)d_in[7];
  const float* ewih_r  = (const float*)d_in[8];
  const float* ewhh_r  = (const float*)d_in[9];
  const float* ebih_r  = (const float*)d_in[10];
  const float* ebhh_r  = (const float*)d_in[11];
  const float* dwih_f  = (const float*)d_in[12];
  const float* dwhh_f  = (const float*)d_in[13];
  const float* dbih_f  = (const float*)d_in[14];
  const float* dbhh_f  = (const float*)d_in[15];
  const float* dwih_r  = (const float*)d_in[16];
  const float* dwhh_r  = (const float*)d_in[17];
  const float* dbih_r  = (const float*)d_in[18];
  const float* dbhh_r  = (const float*)d_in[19];
  const float* cls_w   = (const float*)d_in[20];
  const float* cls_b   = (const float*)d_in[21];

  char* ws = (char*)d_ws;
  unsigned long long* amax = (unsigned long long*)(ws + OFF_AMAX);
  unsigned* flags          = (unsigned*)(ws + OFF_FLAGS);
  float* Xg                = (float*)(ws + OFF_XG);
  float* h_enc             = (float*)(ws + OFF_HENC);
  float* hcat              = (float*)(ws + OFF_HCAT);

  // reset barrier flags + argmax slots (ws is poisoned 0xAA once before timing)
  hipMemsetAsync(d_ws, 0, OFF_XG, stream);

  static bool attr_set = []() {
    hipFuncSetAttribute((const void*)s2s_kernel,
                        hipFuncAttributeMaxDynamicSharedMemorySize, LDS_BYTES);
    return true;
  }();
  (void)attr_set;
  // idempotent safety (cheap; also valid during graph capture)
  hipFuncSetAttribute((const void*)s2s_kernel,
                      hipFuncAttributeMaxDynamicSharedMemorySize, LDS_BYTES);

  hipLaunchKernelGGL(s2s_kernel, dim3(NBLK), dim3(NT), LDS_BYTES, stream,
                     src, tgt, enc_emb, dec_emb,
                     ewih_f, ewhh_f, ebih_f, ebhh_f,
                     ewih_r, ewhh_r, ebih_r, ebhh_r,
                     dwih_f, dwhh_f, dbih_f, dbhh_f,
                     dwih_r, dwhh_r, dbih_r, dbhh_r,
                     cls_w, cls_b,
                     (float*)d_out, amax, flags, Xg, h_enc, hcat);
}

// Round 2
// 27999.310 us; speedup vs baseline: 1.2859x; 1.2859x over previous
//
#include <hip/hip_runtime.h>
#include <stdint.h>

// Seq2Seq (bi-LSTM encoder + greedy LSTM decoder), MI355X gfx950.
// v2: classifier restructured for memory-level parallelism.
//   R1 post-mortem: 30 of 36 ms was the per-step classifier (131 MB cls_w
//   stream) running at 200 GB/s — the `if (rr<nrr)` branch serialized the
//   weight loads (1-2 in flight). v2: all 16 waves, branch-free 8-load
//   batches + unroll 2 (~16 loads in flight/lane), k-split 2 + shfl_xor(32),
//   decoder cell weights reloaded per step to keep VGPR under the 128 cap.
//
// B=32 S=128 T=64 V=32000 E=512 H=512 (4H=2048 gates per cell)

#define NT 1024
#define NBLK 256

constexpr int HSTR = 580;    // enc h-stage LDS row stride (512 + pad, %32==4)
constexpr int XSTR = 1156;   // dec [x|h]-stage stride (1024 + pad, %32==4)
constexpr unsigned LDS_BYTES = 150528;

// workspace layout (bytes)
constexpr size_t OFF_AMAX  = 0;                     // 63*32 u64 = 16128
constexpr size_t OFF_FLAGS = 16128;                 // 256 u32  = 1024
constexpr size_t OFF_XG    = 17408;                 // 256*128*32*16 f32 = 67108864
constexpr size_t OFF_HENC  = OFF_XG + 67108864ULL;  // 2buf*2dir*32*512 f32 = 262144
constexpr size_t OFF_HCAT  = OFF_HENC + 262144ULL;  // 2buf*32*1024 f32 = 262144

__device__ __forceinline__ float sigm(float x) {
  if (x >= 0.f) return 1.f / (1.f + expf(-x));
  float e = expf(x);
  return e / (1.f + e);
}

__device__ __forceinline__ void fma4(const float4& w, const float4& h, float4& a) {
  a.x = fmaf(w.x, h.x, a.x);
  a.y = fmaf(w.y, h.y, a.y);
  a.z = fmaf(w.z, h.z, a.z);
  a.w = fmaf(w.w, h.w, a.w);
}

__device__ __forceinline__ float hsum4(const float4& a) {
  return (a.x + a.y) + (a.z + a.w);
}

// device-scope flag barrier: 256 blocks, thread t<256 polls flags[t].
__device__ __forceinline__ void gbar(unsigned* flags, unsigned gen) {
  __syncthreads();
  if (threadIdx.x == 0) {
    __threadfence();
    __hip_atomic_store(&flags[blockIdx.x], gen, __ATOMIC_RELEASE,
                       __HIP_MEMORY_SCOPE_AGENT);
  }
  if (threadIdx.x < NBLK) {
    while (__hip_atomic_load(&flags[threadIdx.x], __ATOMIC_ACQUIRE,
                             __HIP_MEMORY_SCOPE_AGENT) < gen) {
      __builtin_amdgcn_s_sleep(2);
    }
  }
  __syncthreads();
}

__global__ __launch_bounds__(NT, 4) void s2s_kernel(
    const int* __restrict__ src, const int* __restrict__ tgt,
    const float* __restrict__ enc_emb, const float* __restrict__ dec_emb,
    const float* __restrict__ ewih_f, const float* __restrict__ ewhh_f,
    const float* __restrict__ ebih_f, const float* __restrict__ ebhh_f,
    const float* __restrict__ ewih_r, const float* __restrict__ ewhh_r,
    const float* __restrict__ ebih_r, const float* __restrict__ ebhh_r,
    const float* __restrict__ dwih_f, const float* __restrict__ dwhh_f,
    const float* __restrict__ dbih_f, const float* __restrict__ dbhh_f,
    const float* __restrict__ dwih_r, const float* __restrict__ dwhh_r,
    const float* __restrict__ dbih_r, const float* __restrict__ dbhh_r,
    const float* __restrict__ cls_w, const float* __restrict__ cls_b,
    float* __restrict__ out,
    unsigned long long* __restrict__ amax, unsigned* __restrict__ flags,
    float* __restrict__ Xg, float* __restrict__ h_enc, float* __restrict__ hcat) {
  extern __shared__ float smem[];
  const int tid = threadIdx.x;
  const int bid = blockIdx.x;
  const int d  = bid >> 7;          // 0 = forward, 1 = reverse
  const int u0 = (bid & 127) << 2;  // first of 4 owned LSTM units

  // LDS views per phase (aliased)
  float* hL  = smem;                      // enc: [32][HSTR]
  float* XgL = smem + 32 * HSTR;          // enc: [32*16]
  float* gL  = XgL + 512;                 // enc: [32*16]
  float* xhL = smem;                      // dec: [32][XSTR]
  float* gLd = smem + 32 * XSTR;          // dec: [32*16]
  float4* cT = (float4*)smem;             // cls: [256][33] float4

  // mapping E (phase0 + encoder scan): 2 rows x 4 b per thread, k-split 16
  const int rgE = tid >> 7;               // [0,8)
  const int bpE = (tid >> 4) & 7;         // [0,8)
  const int ksE = tid & 15;               // [0,16)
  const int r0E = rgE * 2, r1E = r0E + 1;
  const int growE0 = (r0E & 3) * 512 + u0 + (r0E >> 2);
  const int growE1 = (r1E & 3) * 512 + u0 + (r1E >> 2);
  // mapping D (decoder cells): 2 rows x 8 b per thread, k-split 32 over K=1024
  const int rgD = tid >> 7;
  const int bpD = (tid >> 5) & 3;         // [0,4)
  const int ksD = tid & 31;               // [0,32)
  const int r0D = rgD * 2, r1D = r0D + 1;
  const int growD0 = (r0D & 3) * 512 + u0 + (r0D >> 2);
  const int growD1 = (r1D & 3) * 512 + u0 + (r1D >> 2);

  const float* ewih = d ? ewih_r : ewih_f;
  const float* ewhh = d ? ewhh_r : ewhh_f;
  const float* ebih = d ? ebih_r : ebih_f;
  const float* ebhh = d ? ebhh_r : ebhh_f;
  const float* dwih = d ? dwih_r : dwih_f;
  const float* dwhh = d ? dwhh_r : dwhh_f;
  const float* dbih = d ? dbih_r : dbih_f;
  const float* dbhh = d ? dbhh_r : dbhh_f;

  float4 wA[8], wB[8];
  float biasA, biasB;
  float c_reg = 0.f;   // cell state for threads tid<128 (b=tid&31, j=tid>>5)
  unsigned gen = 0;

  // ---------------- phase 0: Xg = emb(src) @ wih^T + bih + bhh ----------------
#pragma unroll
  for (int i4 = 0; i4 < 8; ++i4) {
    wA[i4] = *(const float4*)(ewih + (size_t)growE0 * 512 + ksE * 32 + i4 * 4);
    wB[i4] = *(const float4*)(ewih + (size_t)growE1 * 512 + ksE * 32 + i4 * 4);
  }
  biasA = ebih[growE0] + ebhh[growE0];
  biasB = ebih[growE1] + ebhh[growE1];

  for (int t = 0; t < 128; ++t) {
    {  // stage x = enc_emb[src[b][t]] into hL
      int b = tid >> 5, i = tid & 31;
      int tok = src[b * 128 + t];
      const float* row = enc_emb + (size_t)tok * 512;
#pragma unroll
      for (int q = 0; q < 4; ++q) {
        int k = (i + 32 * q) * 4;
        float4 v = *(const float4*)(row + k);
        int pc = k + ((k >> 5) << 2);
        *(float4*)(hL + b * HSTR + pc) = v;
      }
    }
    __syncthreads();
    for (int gi = 0; gi < 4; ++gi) {
      int b = bpE * 4 + gi;
      const float* hb = hL + b * HSTR + ksE * 36;
      float4 a0 = {0, 0, 0, 0}, a1 = {0, 0, 0, 0};
#pragma unroll
      for (int i4 = 0; i4 < 8; ++i4) {
        float4 h4 = *(const float4*)(hb + i4 * 4);
        fma4(wA[i4], h4, a0);
        fma4(wB[i4], h4, a1);
      }
      float s0 = hsum4(a0), s1 = hsum4(a1);
#pragma unroll
      for (int m = 1; m <= 8; m <<= 1) {
        s0 += __shfl_xor(s0, m, 64);
        s1 += __shfl_xor(s1, m, 64);
      }
      if (ksE == 0) {
        float* xgp = Xg + ((size_t)bid << 16) + t * 512 + b * 16;
        xgp[r0E] = s0 + biasA;
        xgp[r1E] = s1 + biasB;
      }
    }
    __syncthreads();
  }

  // init h_enc[buf0] = 0 for owned units; zero out[:,0,:] slice
  if (tid < 128) {
    int b = tid & 31, j = tid >> 5;
    h_enc[((0 * 2 + d) * 32 + b) * 512 + u0 + j] = 0.f;
  }
  for (int i = tid; i < 4000; i += NT) {
    int b = i & 31, vv = i >> 5;  // vv < 125
    out[(size_t)b * 64 * 32000 + bid * 125 + vv] = 0.f;
  }
  gbar(flags, ++gen);

  // ---------------- encoder scan: 128 steps ----------------
#pragma unroll
  for (int i4 = 0; i4 < 8; ++i4) {
    wA[i4] = *(const float4*)(ewhh + (size_t)growE0 * 512 + ksE * 32 + i4 * 4);
    wB[i4] = *(const float4*)(ewhh + (size_t)growE1 * 512 + ksE * 32 + i4 * 4);
  }
  int cur = 0;
  for (int s = 0; s < 128; ++s) {
    const int td = d ? (127 - s) : s;
    {  // stage h_enc[cur][d] -> hL; stage this block's Xg slice -> XgL
      int b = tid >> 5, i = tid & 31;
      const float* hr = h_enc + ((size_t)(cur * 2 + d) * 32 + b) * 512;
#pragma unroll
      for (int q = 0; q < 4; ++q) {
        int k = (i + 32 * q) * 4;
        float4 v = *(const float4*)(hr + k);
        int pc = k + ((k >> 5) << 2);
        *(float4*)(hL + b * HSTR + pc) = v;
      }
      if (tid < 128) {
        ((float4*)XgL)[tid] =
            *(const float4*)(Xg + ((size_t)bid << 16) + td * 512 + tid * 4);
      }
    }
    __syncthreads();
    for (int gi = 0; gi < 4; ++gi) {
      int b = bpE * 4 + gi;
      const float* hb = hL + b * HSTR + ksE * 36;
      float4 a0 = {0, 0, 0, 0}, a1 = {0, 0, 0, 0};
#pragma unroll
      for (int i4 = 0; i4 < 8; ++i4) {
        float4 h4 = *(const float4*)(hb + i4 * 4);
        fma4(wA[i4], h4, a0);
        fma4(wB[i4], h4, a1);
      }
      float s0 = hsum4(a0), s1 = hsum4(a1);
#pragma unroll
      for (int m = 1; m <= 8; m <<= 1) {
        s0 += __shfl_xor(s0, m, 64);
        s1 += __shfl_xor(s1, m, 64);
      }
      if (ksE == 0) {
        gL[b * 16 + r0E] = s0 + XgL[b * 16 + r0E];
        gL[b * 16 + r1E] = s1 + XgL[b * 16 + r1E];
      }
    }
    __syncthreads();
    if (tid < 128) {
      int b = tid & 31, j = tid >> 5;
      float g_i = gL[b * 16 + (j << 2) + 0];
      float g_f = gL[b * 16 + (j << 2) + 1];
      float g_g = gL[b * 16 + (j << 2) + 2];
      float g_o = gL[b * 16 + (j << 2) + 3];
      c_reg = sigm(g_f) * c_reg + sigm(g_i) * tanhf(g_g);
      float h = sigm(g_o) * tanhf(c_reg);
      h_enc[(((cur ^ 1) * 2 + d) * 32 + b) * 512 + u0 + j] = h;
      if (s == 127) hcat[b * 1024 + d * 512 + u0 + j] = h;  // buf 0
    }
    gbar(flags, ++gen);
    cur ^= 1;
  }

  // ---------------- decoder: 63 steps ----------------
  for (int t = 0; t < 63; ++t) {
    const int p = t & 1;
    {  // stage [x | h_d] into xhL
      int b = tid >> 5, i = tid & 31;
      int tok;
      if (t == 0) {
        tok = tgt[b * 64];
      } else {
        unsigned long long kv = amax[(t - 1) * 32 + b];
        tok = (int)(0xFFFFFFFFu - (unsigned)(kv & 0xFFFFFFFFull));
      }
      const float* xr = dec_emb + (size_t)tok * 512;
      const float* hr = hcat + (size_t)p * 32768 + b * 1024 + d * 512;
#pragma unroll
      for (int q = 0; q < 4; ++q) {
        int k = (i + 32 * q) * 4;
        float4 v = *(const float4*)(xr + k);
        int pc = k + ((k >> 5) << 2);
        *(float4*)(xhL + b * XSTR + pc) = v;
      }
#pragma unroll
      for (int q = 0; q < 4; ++q) {
        int k = (i + 32 * q) * 4;
        float4 v = *(const float4*)(hr + k);
        int c2 = 512 + k;
        int pc = c2 + ((c2 >> 5) << 2);
        *(float4*)(xhL + b * XSTR + pc) = v;
      }
    }
    // reload decoder cell weights each step (frees 64 VGPR for classifier)
    {
      const float* s0p = (ksD < 16) ? (dwih + (size_t)growD0 * 512 + ksD * 32)
                                    : (dwhh + (size_t)growD0 * 512 + (ksD - 16) * 32);
      const float* s1p = (ksD < 16) ? (dwih + (size_t)growD1 * 512 + ksD * 32)
                                    : (dwhh + (size_t)growD1 * 512 + (ksD - 16) * 32);
#pragma unroll
      for (int i4 = 0; i4 < 8; ++i4) {
        wA[i4] = *(const float4*)(s0p + i4 * 4);
        wB[i4] = *(const float4*)(s1p + i4 * 4);
      }
      biasA = dbih[growD0] + dbhh[growD0];
      biasB = dbih[growD1] + dbhh[growD1];
    }
    __syncthreads();
    for (int gi = 0; gi < 8; ++gi) {
      int b = bpD * 8 + gi;
      const float* hb = xhL + b * XSTR + ksD * 36;
      float4 a0 = {0, 0, 0, 0}, a1 = {0, 0, 0, 0};
#pragma unroll
      for (int i4 = 0; i4 < 8; ++i4) {
        float4 h4 = *(const float4*)(hb + i4 * 4);
        fma4(wA[i4], h4, a0);
        fma4(wB[i4], h4, a1);
      }
      float s0 = hsum4(a0), s1 = hsum4(a1);
#pragma unroll
      for (int m = 1; m <= 16; m <<= 1) {
        s0 += __shfl_xor(s0, m, 64);
        s1 += __shfl_xor(s1, m, 64);
      }
      if (ksD == 0) {
        gLd[b * 16 + r0D] = s0 + biasA;
        gLd[b * 16 + r1D] = s1 + biasB;
      }
    }
    __syncthreads();
    if (tid < 128) {
      int b = tid & 31, j = tid >> 5;
      float g_i = gLd[b * 16 + (j << 2) + 0];
      float g_f = gLd[b * 16 + (j << 2) + 1];
      float g_g = gLd[b * 16 + (j << 2) + 2];
      float g_o = gLd[b * 16 + (j << 2) + 3];
      c_reg = sigm(g_f) * c_reg + sigm(g_i) * tanhf(g_g);
      float h = sigm(g_o) * tanhf(c_reg);
      hcat[(size_t)(p ^ 1) * 32768 + b * 1024 + d * 512 + u0 + j] = h;
    }
    gbar(flags, ++gen);

    // ---- classifier v2: logits = hcat[p^1] @ cls_w^T + cls_b, argmax ----
    // All 16 waves; wave wid owns rows [wid*8, wid*8+8) of this block's 125
    // (clamped at 124; duplicate computation is bit-identical, stores guarded).
    // k-split 2 across half-waves; 8 batched loads + unroll 2 for MLP.
    {
      int b = tid >> 5, kk = tid & 31;
      const float* hr = hcat + (size_t)(p ^ 1) * 32768 + b * 1024;
#pragma unroll
      for (int it = 0; it < 8; ++it) {
        int k4 = kk + it * 32;
        cT[k4 * 33 + b] = *(const float4*)(hr + k4 * 4);
      }
    }
    __syncthreads();
    {
      const int wid = tid >> 6;
      const int lane = tid & 63;
      const int cb = lane & 31;
      const int ks = lane >> 5;
      float acc[8] = {0.f, 0.f, 0.f, 0.f, 0.f, 0.f, 0.f, 0.f};
      const float* wrow[8];
#pragma unroll
      for (int rr = 0; rr < 8; ++rr) {
        int lr = wid * 8 + rr;
        if (lr > 124) lr = 124;
        wrow[rr] = cls_w + (size_t)(bid * 125 + lr) * 1024 + ks * 512;
      }
      const float4* hp = cT + ks * 128 * 33 + cb;
#pragma unroll 2
      for (int k4 = 0; k4 < 128; ++k4) {
        float4 w4[8];
#pragma unroll
        for (int rr = 0; rr < 8; ++rr)
          w4[rr] = *(const float4*)(wrow[rr] + k4 * 4);
        float4 h4 = hp[k4 * 33];
#pragma unroll
        for (int rr = 0; rr < 8; ++rr) {
          acc[rr] = fmaf(w4[rr].x, h4.x,
                    fmaf(w4[rr].y, h4.y,
                    fmaf(w4[rr].z, h4.z,
                    fmaf(w4[rr].w, h4.w, acc[rr]))));
        }
      }
      unsigned long long bestkey = 0ull;
#pragma unroll
      for (int rr = 0; rr < 8; ++rr) {
        acc[rr] += __shfl_xor(acc[rr], 32, 64);
        int lr = wid * 8 + rr;
        if (ks == 0 && lr < 125) {
          int vrow = bid * 125 + lr;
          float lg = acc[rr] + cls_b[vrow];
          out[((size_t)cb * 64 + (t + 1)) * 32000 + vrow] = lg;
          unsigned u = __float_as_uint(lg);
          u = (u & 0x80000000u) ? ~u : (u | 0x80000000u);
          unsigned long long key = ((unsigned long long)u << 32) |
                                   (0xFFFFFFFFu - (unsigned)vrow);
          bestkey = key > bestkey ? key : bestkey;
        }
      }
      if (ks == 0) atomicMax(&amax[t * 32 + cb], bestkey);
    }
    gbar(flags, ++gen);
  }
}

extern "C" void kernel_launch(void* const* d_in, const int* in_sizes, int n_in,
                              void* d_out, int out_size, void* d_ws, size_t ws_size,
                              hipStream_t stream) {
  (void)in_sizes; (void)n_in; (void)out_size; (void)ws_size;
  const int*   src     = (const int*)d_in[0];
  const int*   tgt     = (const int*)d_in[1];
  const float* enc_emb = (const float*)d_in[2];
  const float* dec_emb = (const float*)d_in[3];
  const float* ewih_f  = (const float*)d_in[4];
  const float* ewhh_f  = (const float*)d_in[5];
  const float* ebih_f  = (const float*)d_in[6];
  const float* ebhh_f  = (const float*)d_in[7];
  const float* ewih_r  = (const float*)d_in[8];
  const float* ewhh_r  = (const float*)d_in[9];
  const float* ebih_r  = (const float*)d_in[10];
  const float* ebhh_r  = (const float*)d_in[11];
  const float* dwih_f  = (const float*)d_in[12];
  const float* dwhh_f  = (const float*)d_in[13];
  const float* dbih_f  = (const float*)d_in[14];
  const float* dbhh_f  = (const float*)d_in[15];
  const float* dwih_r  = (const float*)d_in[16];
  const float* dwhh_r  = (const float*)d_in[17];
  const float* dbih_r  = (const float*)d_in[18];
  const float* dbhh_r  = (const float*)d_in[19];
  const float* cls_w   = (const float*)d_in[20];
  const float* cls_b   = (const float*)d_in[21];

  char* ws = (char*)d_ws;
  unsigned long long* amax = (unsigned long long*)(ws + OFF_AMAX);
  unsigned* flags          = (unsigned*)(ws + OFF_FLAGS);
  float* Xg                = (float*)(ws + OFF_XG);
  float* h_enc             = (float*)(ws + OFF_HENC);
  float* hcat              = (float*)(ws + OFF_HCAT);

  // reset barrier flags + argmax slots (ws is poisoned 0xAA once before timing)
  hipMemsetAsync(d_ws, 0, OFF_XG, stream);

  static bool attr_set = []() {
    hipFuncSetAttribute((const void*)s2s_kernel,
                        hipFuncAttributeMaxDynamicSharedMemorySize, LDS_BYTES);
    return true;
  }();
  (void)attr_set;
  hipFuncSetAttribute((const void*)s2s_kernel,
                      hipFuncAttributeMaxDynamicSharedMemorySize, LDS_BYTES);

  hipLaunchKernelGGL(s2s_kernel, dim3(NBLK), dim3(NT), LDS_BYTES, stream,
                     src, tgt, enc_emb, dec_emb,
                     ewih_f, ewhh_f, ebih_f, ebhh_f,
                     ewih_r, ewhh_r, ebih_r, ebhh_r,
                     dwih_f, dwhh_f, dbih_f, dbhh_f,
                     dwih_r, dwhh_r, dbih_r, dbhh_r,
                     cls_w, cls_b,
                     (float*)d_out, amax, flags, Xg, h_enc, hcat);
}

// Round 3
// 19288.960 us; speedup vs baseline: 1.8666x; 1.4516x over previous
//
#include <hip/hip_runtime.h>
#include <stdint.h>

// Seq2Seq (bi-LSTM encoder + greedy LSTM decoder), MI355X gfx950.
// v3: classifier with lane-coalesced weight stream.
//   R2 post-mortem: VGPR=64, ~2 loads in flight/wave; root cause = wave-
//   uniform 16B broadcast loads (16B/instr/wave). v3: lanes partition K
//   (rg=4 rows x kc=16 k-chunks), 256B contiguous per row-group per instr,
//   h staged row-major in LDS (conflict-free b128), acc[2][32]/lane,
//   butterfly-reduce over kc + static select tree, LDS-staged coalesced
//   logit writeback, LDS-atomic argmax pre-reduce.
//
// B=32 S=128 T=64 V=32000 E=512 H=512 (4H=2048 gates per cell)

#define NT 1024
#define NBLK 256

constexpr int HSTR = 580;    // enc h-stage LDS row stride (512 + pad, %32==4)
constexpr int XSTR = 1156;   // dec [x|h]-stage stride (1024 + pad, %32==4)
constexpr unsigned LDS_BYTES = 150528;

// workspace layout (bytes)
constexpr size_t OFF_AMAX  = 0;                     // 63*32 u64 = 16128
constexpr size_t OFF_FLAGS = 16128;                 // 256 u32  = 1024
constexpr size_t OFF_XG    = 17408;                 // 256*128*32*16 f32 = 67108864
constexpr size_t OFF_HENC  = OFF_XG + 67108864ULL;  // 2buf*2dir*32*512 f32 = 262144
constexpr size_t OFF_HCAT  = OFF_HENC + 262144ULL;  // 2buf*32*1024 f32 = 262144

__device__ __forceinline__ float sigm(float x) {
  if (x >= 0.f) return 1.f / (1.f + expf(-x));
  float e = expf(x);
  return e / (1.f + e);
}

__device__ __forceinline__ void fma4(const float4& w, const float4& h, float4& a) {
  a.x = fmaf(w.x, h.x, a.x);
  a.y = fmaf(w.y, h.y, a.y);
  a.z = fmaf(w.z, h.z, a.z);
  a.w = fmaf(w.w, h.w, a.w);
}

__device__ __forceinline__ float hsum4(const float4& a) {
  return (a.x + a.y) + (a.z + a.w);
}

__device__ __forceinline__ float dot4(const float4& w, const float4& h, float acc) {
  return fmaf(w.x, h.x, fmaf(w.y, h.y, fmaf(w.z, h.z, fmaf(w.w, h.w, acc))));
}

// device-scope flag barrier: 256 blocks, thread t<256 polls flags[t].
__device__ __forceinline__ void gbar(unsigned* flags, unsigned gen) {
  __syncthreads();
  if (threadIdx.x == 0) {
    __threadfence();
    __hip_atomic_store(&flags[blockIdx.x], gen, __ATOMIC_RELEASE,
                       __HIP_MEMORY_SCOPE_AGENT);
  }
  if (threadIdx.x < NBLK) {
    while (__hip_atomic_load(&flags[threadIdx.x], __ATOMIC_ACQUIRE,
                             __HIP_MEMORY_SCOPE_AGENT) < gen) {
      __builtin_amdgcn_s_sleep(2);
    }
  }
  __syncthreads();
}

__global__ __launch_bounds__(NT, 4) void s2s_kernel(
    const int* __restrict__ src, const int* __restrict__ tgt,
    const float* __restrict__ enc_emb, const float* __restrict__ dec_emb,
    const float* __restrict__ ewih_f, const float* __restrict__ ewhh_f,
    const float* __restrict__ ebih_f, const float* __restrict__ ebhh_f,
    const float* __restrict__ ewih_r, const float* __restrict__ ewhh_r,
    const float* __restrict__ ebih_r, const float* __restrict__ ebhh_r,
    const float* __restrict__ dwih_f, const float* __restrict__ dwhh_f,
    const float* __restrict__ dbih_f, const float* __restrict__ dbhh_f,
    const float* __restrict__ dwih_r, const float* __restrict__ dwhh_r,
    const float* __restrict__ dbih_r, const float* __restrict__ dbhh_r,
    const float* __restrict__ cls_w, const float* __restrict__ cls_b,
    float* __restrict__ out,
    unsigned long long* __restrict__ amax, unsigned* __restrict__ flags,
    float* __restrict__ Xg, float* __restrict__ h_enc, float* __restrict__ hcat) {
  extern __shared__ float smem[];
  const int tid = threadIdx.x;
  const int bid = blockIdx.x;
  const int d  = bid >> 7;          // 0 = forward, 1 = reverse
  const int u0 = (bid & 127) << 2;  // first of 4 owned LSTM units

  // LDS views per phase (aliased)
  float* hL  = smem;                      // enc: [32][HSTR]
  float* XgL = smem + 32 * HSTR;          // enc: [32*16]
  float* gL  = XgL + 512;                 // enc: [32*16]
  float* xhL = smem;                      // dec cell: [32][XSTR]
  float* gLd = smem + 32 * XSTR;          // dec cell: [32*16]  (floats 36992..37504)
  // classifier phase: cH float4[8192] at floats 0..32768 (128 KB)
  //                   oL [32][130] at floats 32768..36928
  //                   amaxL u64[32] at floats 37504..37568 (bytes 150016..150272)
  float* oL = smem + 32768;
  unsigned long long* amaxL = (unsigned long long*)(smem + 37504);

  // mapping E (phase0 + encoder scan): 2 rows x 4 b per thread, k-split 16
  const int rgE = tid >> 7;               // [0,8)
  const int bpE = (tid >> 4) & 7;         // [0,8)
  const int ksE = tid & 15;               // [0,16)
  const int r0E = rgE * 2, r1E = r0E + 1;
  const int growE0 = (r0E & 3) * 512 + u0 + (r0E >> 2);
  const int growE1 = (r1E & 3) * 512 + u0 + (r1E >> 2);
  // mapping D (decoder cells): 2 rows x 8 b per thread, k-split 32 over K=1024
  const int rgD = tid >> 7;
  const int bpD = (tid >> 5) & 3;         // [0,4)
  const int ksD = tid & 31;               // [0,32)
  const int r0D = rgD * 2, r1D = r0D + 1;
  const int growD0 = (r0D & 3) * 512 + u0 + (r0D >> 2);
  const int growD1 = (r1D & 3) * 512 + u0 + (r1D >> 2);

  const float* ewih = d ? ewih_r : ewih_f;
  const float* ewhh = d ? ewhh_r : ewhh_f;
  const float* ebih = d ? ebih_r : ebih_f;
  const float* ebhh = d ? ebhh_r : ebhh_f;
  const float* dwih = d ? dwih_r : dwih_f;
  const float* dwhh = d ? dwhh_r : dwhh_f;
  const float* dbih = d ? dbih_r : dbih_f;
  const float* dbhh = d ? dbhh_r : dbhh_f;

  float4 wA[8], wB[8];
  float biasA, biasB;
  float c_reg = 0.f;   // cell state for threads tid<128 (b=tid&31, j=tid>>5)
  unsigned gen = 0;

  // ---------------- phase 0: Xg = emb(src) @ wih^T + bih + bhh ----------------
#pragma unroll
  for (int i4 = 0; i4 < 8; ++i4) {
    wA[i4] = *(const float4*)(ewih + (size_t)growE0 * 512 + ksE * 32 + i4 * 4);
    wB[i4] = *(const float4*)(ewih + (size_t)growE1 * 512 + ksE * 32 + i4 * 4);
  }
  biasA = ebih[growE0] + ebhh[growE0];
  biasB = ebih[growE1] + ebhh[growE1];

  for (int t = 0; t < 128; ++t) {
    {  // stage x = enc_emb[src[b][t]] into hL
      int b = tid >> 5, i = tid & 31;
      int tok = src[b * 128 + t];
      const float* row = enc_emb + (size_t)tok * 512;
#pragma unroll
      for (int q = 0; q < 4; ++q) {
        int k = (i + 32 * q) * 4;
        float4 v = *(const float4*)(row + k);
        int pc = k + ((k >> 5) << 2);
        *(float4*)(hL + b * HSTR + pc) = v;
      }
    }
    __syncthreads();
    for (int gi = 0; gi < 4; ++gi) {
      int b = bpE * 4 + gi;
      const float* hb = hL + b * HSTR + ksE * 36;
      float4 a0 = {0, 0, 0, 0}, a1 = {0, 0, 0, 0};
#pragma unroll
      for (int i4 = 0; i4 < 8; ++i4) {
        float4 h4 = *(const float4*)(hb + i4 * 4);
        fma4(wA[i4], h4, a0);
        fma4(wB[i4], h4, a1);
      }
      float s0 = hsum4(a0), s1 = hsum4(a1);
#pragma unroll
      for (int m = 1; m <= 8; m <<= 1) {
        s0 += __shfl_xor(s0, m, 64);
        s1 += __shfl_xor(s1, m, 64);
      }
      if (ksE == 0) {
        float* xgp = Xg + ((size_t)bid << 16) + t * 512 + b * 16;
        xgp[r0E] = s0 + biasA;
        xgp[r1E] = s1 + biasB;
      }
    }
    __syncthreads();
  }

  // init h_enc[buf0] = 0 for owned units; zero out[:,0,:] slice
  if (tid < 128) {
    int b = tid & 31, j = tid >> 5;
    h_enc[((0 * 2 + d) * 32 + b) * 512 + u0 + j] = 0.f;
  }
  for (int i = tid; i < 4000; i += NT) {
    int b = i & 31, vv = i >> 5;  // vv < 125
    out[(size_t)b * 64 * 32000 + bid * 125 + vv] = 0.f;
  }
  gbar(flags, ++gen);

  // ---------------- encoder scan: 128 steps ----------------
#pragma unroll
  for (int i4 = 0; i4 < 8; ++i4) {
    wA[i4] = *(const float4*)(ewhh + (size_t)growE0 * 512 + ksE * 32 + i4 * 4);
    wB[i4] = *(const float4*)(ewhh + (size_t)growE1 * 512 + ksE * 32 + i4 * 4);
  }
  int cur = 0;
  for (int s = 0; s < 128; ++s) {
    const int td = d ? (127 - s) : s;
    {  // stage h_enc[cur][d] -> hL; stage this block's Xg slice -> XgL
      int b = tid >> 5, i = tid & 31;
      const float* hr = h_enc + ((size_t)(cur * 2 + d) * 32 + b) * 512;
#pragma unroll
      for (int q = 0; q < 4; ++q) {
        int k = (i + 32 * q) * 4;
        float4 v = *(const float4*)(hr + k);
        int pc = k + ((k >> 5) << 2);
        *(float4*)(hL + b * HSTR + pc) = v;
      }
      if (tid < 128) {
        ((float4*)XgL)[tid] =
            *(const float4*)(Xg + ((size_t)bid << 16) + td * 512 + tid * 4);
      }
    }
    __syncthreads();
    for (int gi = 0; gi < 4; ++gi) {
      int b = bpE * 4 + gi;
      const float* hb = hL + b * HSTR + ksE * 36;
      float4 a0 = {0, 0, 0, 0}, a1 = {0, 0, 0, 0};
#pragma unroll
      for (int i4 = 0; i4 < 8; ++i4) {
        float4 h4 = *(const float4*)(hb + i4 * 4);
        fma4(wA[i4], h4, a0);
        fma4(wB[i4], h4, a1);
      }
      float s0 = hsum4(a0), s1 = hsum4(a1);
#pragma unroll
      for (int m = 1; m <= 8; m <<= 1) {
        s0 += __shfl_xor(s0, m, 64);
        s1 += __shfl_xor(s1, m, 64);
      }
      if (ksE == 0) {
        gL[b * 16 + r0E] = s0 + XgL[b * 16 + r0E];
        gL[b * 16 + r1E] = s1 + XgL[b * 16 + r1E];
      }
    }
    __syncthreads();
    if (tid < 128) {
      int b = tid & 31, j = tid >> 5;
      float g_i = gL[b * 16 + (j << 2) + 0];
      float g_f = gL[b * 16 + (j << 2) + 1];
      float g_g = gL[b * 16 + (j << 2) + 2];
      float g_o = gL[b * 16 + (j << 2) + 3];
      c_reg = sigm(g_f) * c_reg + sigm(g_i) * tanhf(g_g);
      float h = sigm(g_o) * tanhf(c_reg);
      h_enc[(((cur ^ 1) * 2 + d) * 32 + b) * 512 + u0 + j] = h;
      if (s == 127) hcat[b * 1024 + d * 512 + u0 + j] = h;  // buf 0
    }
    gbar(flags, ++gen);
    cur ^= 1;
  }

  // ---------------- decoder: 63 steps ----------------
  for (int t = 0; t < 63; ++t) {
    const int p = t & 1;
    {  // stage [x | h_d] into xhL
      int b = tid >> 5, i = tid & 31;
      int tok;
      if (t == 0) {
        tok = tgt[b * 64];
      } else {
        unsigned long long kv = amax[(t - 1) * 32 + b];
        tok = (int)(0xFFFFFFFFu - (unsigned)(kv & 0xFFFFFFFFull));
      }
      const float* xr = dec_emb + (size_t)tok * 512;
      const float* hr = hcat + (size_t)p * 32768 + b * 1024 + d * 512;
#pragma unroll
      for (int q = 0; q < 4; ++q) {
        int k = (i + 32 * q) * 4;
        float4 v = *(const float4*)(xr + k);
        int pc = k + ((k >> 5) << 2);
        *(float4*)(xhL + b * XSTR + pc) = v;
      }
#pragma unroll
      for (int q = 0; q < 4; ++q) {
        int k = (i + 32 * q) * 4;
        float4 v = *(const float4*)(hr + k);
        int c2 = 512 + k;
        int pc = c2 + ((c2 >> 5) << 2);
        *(float4*)(xhL + b * XSTR + pc) = v;
      }
    }
    // reload decoder cell weights each step (frees VGPR for classifier)
    {
      const float* s0p = (ksD < 16) ? (dwih + (size_t)growD0 * 512 + ksD * 32)
                                    : (dwhh + (size_t)growD0 * 512 + (ksD - 16) * 32);
      const float* s1p = (ksD < 16) ? (dwih + (size_t)growD1 * 512 + ksD * 32)
                                    : (dwhh + (size_t)growD1 * 512 + (ksD - 16) * 32);
#pragma unroll
      for (int i4 = 0; i4 < 8; ++i4) {
        wA[i4] = *(const float4*)(s0p + i4 * 4);
        wB[i4] = *(const float4*)(s1p + i4 * 4);
      }
      biasA = dbih[growD0] + dbhh[growD0];
      biasB = dbih[growD1] + dbhh[growD1];
    }
    __syncthreads();
    for (int gi = 0; gi < 8; ++gi) {
      int b = bpD * 8 + gi;
      const float* hb = xhL + b * XSTR + ksD * 36;
      float4 a0 = {0, 0, 0, 0}, a1 = {0, 0, 0, 0};
#pragma unroll
      for (int i4 = 0; i4 < 8; ++i4) {
        float4 h4 = *(const float4*)(hb + i4 * 4);
        fma4(wA[i4], h4, a0);
        fma4(wB[i4], h4, a1);
      }
      float s0 = hsum4(a0), s1 = hsum4(a1);
#pragma unroll
      for (int m = 1; m <= 16; m <<= 1) {
        s0 += __shfl_xor(s0, m, 64);
        s1 += __shfl_xor(s1, m, 64);
      }
      if (ksD == 0) {
        gLd[b * 16 + r0D] = s0 + biasA;
        gLd[b * 16 + r1D] = s1 + biasB;
      }
    }
    __syncthreads();
    if (tid < 128) {
      int b = tid & 31, j = tid >> 5;
      float g_i = gLd[b * 16 + (j << 2) + 0];
      float g_f = gLd[b * 16 + (j << 2) + 1];
      float g_g = gLd[b * 16 + (j << 2) + 2];
      float g_o = gLd[b * 16 + (j << 2) + 3];
      c_reg = sigm(g_f) * c_reg + sigm(g_i) * tanhf(g_g);
      float h = sigm(g_o) * tanhf(c_reg);
      hcat[(size_t)(p ^ 1) * 32768 + b * 1024 + d * 512 + u0 + j] = h;
    }
    gbar(flags, ++gen);

    // ---- classifier v3: logits = h @ cls_w^T + cls_b, argmax ----
    {  // stage h (plain row-major [32][1024]) into cH; zero amaxL
      const float* hr = hcat + (size_t)(p ^ 1) * 32768;
      float4* cH = (float4*)smem;
#pragma unroll
      for (int q = 0; q < 8; ++q) {
        int f = tid + q * 1024;
        cH[f] = *(const float4*)(hr + f * 4);
      }
      if (tid < 32) amaxL[tid] = 0ull;
    }
    __syncthreads();
    {
      const int wid = tid >> 6, lane = tid & 63;
      const int rg = lane >> 4;   // [0,4): this lane owns rows rg and rg+4
      const int kc = lane & 15;   // k-chunk within row
      const float4* cH = (const float4*)smem;
      const int lrA = wid * 8 + rg;        // 0..123, always valid
      const int lrB = lrA + 4;             // up to 127; rows >=125 invalid
      const int lrBc = lrB > 124 ? 124 : lrB;
      const int vrA = bid * 125 + lrA;
      const int vrB = bid * 125 + lrBc;
      const float4* wpA = (const float4*)(cls_w + (size_t)vrA * 1024) + kc;
      const float4* wpB = (const float4*)(cls_w + (size_t)vrB * 1024) + kc;
      float accA[32], accB[32];
#pragma unroll
      for (int b = 0; b < 32; ++b) { accA[b] = 0.f; accB[b] = 0.f; }
      float4 wa = wpA[0], wb = wpB[0];
      for (int q = 0; q < 16; ++q) {
        const int qn = (q + 1) & 15;
        float4 wan = wpA[qn * 16];   // prefetch next k-chunk (coalesced 256B/row-group)
        float4 wbn = wpB[qn * 16];
        const float4* hp0 = cH + q * 16 + kc;
#pragma unroll
        for (int b = 0; b < 32; ++b) {
          const float4* hb = (b < 16) ? hp0 : (hp0 + 4096);
          float4 h4 = hb[(b & 15) * 256];
          accA[b] = dot4(wa, h4, accA[b]);
          accB[b] = dot4(wb, h4, accB[b]);
        }
        wa = wan; wb = wbn;
      }
      // butterfly-sum over the 16 kc lanes (masks 1,2,4,8)
#pragma unroll
      for (int b = 0; b < 32; ++b) {
#pragma unroll
        for (int m = 1; m <= 8; m <<= 1) {
          accA[b] += __shfl_xor(accA[b], m, 64);
          accB[b] += __shfl_xor(accB[b], m, 64);
        }
      }
      // static select tree: this lane keeps b0=kc, b1=kc+16
      float a0[8], a1[8], b0v[8], b1v[8];
#pragma unroll
      for (int i = 0; i < 8; ++i) {
        a0[i]  = (kc & 8) ? accA[i + 8]  : accA[i];
        a1[i]  = (kc & 8) ? accA[i + 24] : accA[i + 16];
        b0v[i] = (kc & 8) ? accB[i + 8]  : accB[i];
        b1v[i] = (kc & 8) ? accB[i + 24] : accB[i + 16];
      }
#pragma unroll
      for (int i = 0; i < 4; ++i) {
        a0[i]  = (kc & 4) ? a0[i + 4]  : a0[i];
        a1[i]  = (kc & 4) ? a1[i + 4]  : a1[i];
        b0v[i] = (kc & 4) ? b0v[i + 4] : b0v[i];
        b1v[i] = (kc & 4) ? b1v[i + 4] : b1v[i];
      }
#pragma unroll
      for (int i = 0; i < 2; ++i) {
        a0[i]  = (kc & 2) ? a0[i + 2]  : a0[i];
        a1[i]  = (kc & 2) ? a1[i + 2]  : a1[i];
        b0v[i] = (kc & 2) ? b0v[i + 2] : b0v[i];
        b1v[i] = (kc & 2) ? b1v[i + 2] : b1v[i];
      }
      a0[0]  = (kc & 1) ? a0[1]  : a0[0];
      a1[0]  = (kc & 1) ? a1[1]  : a1[0];
      b0v[0] = (kc & 1) ? b0v[1] : b0v[0];
      b1v[0] = (kc & 1) ? b1v[1] : b1v[0];

      const float cbA = cls_b[vrA], cbB = cls_b[vrB];
      const float lgA0 = a0[0] + cbA;   // (row lrA, b=kc)
      const float lgA1 = a1[0] + cbA;   // (row lrA, b=kc+16)
      const float lgB0 = b0v[0] + cbB;  // (row lrB, b=kc)
      const float lgB1 = b1v[0] + cbB;  // (row lrB, b=kc+16)

      // stage into oL[b][row_local] (stride 130 -> conflict-free) for coalesced writeback
      oL[kc * 130 + lrA] = lgA0;
      oL[(kc + 16) * 130 + lrA] = lgA1;
      oL[kc * 130 + lrB] = lgB0;        // rows 125..127 staged but filtered later
      oL[(kc + 16) * 130 + lrB] = lgB1;

      // argmax keys (ordered-float <<32 | ~vrow  => max = first-index-wins argmax)
      unsigned uA0 = __float_as_uint(lgA0); uA0 = (uA0 & 0x80000000u) ? ~uA0 : (uA0 | 0x80000000u);
      unsigned uA1 = __float_as_uint(lgA1); uA1 = (uA1 & 0x80000000u) ? ~uA1 : (uA1 | 0x80000000u);
      unsigned long long bk0 = ((unsigned long long)uA0 << 32) | (0xFFFFFFFFu - (unsigned)vrA);
      unsigned long long bk1 = ((unsigned long long)uA1 << 32) | (0xFFFFFFFFu - (unsigned)vrA);
      if (lrB < 125) {
        unsigned uB0 = __float_as_uint(lgB0); uB0 = (uB0 & 0x80000000u) ? ~uB0 : (uB0 | 0x80000000u);
        unsigned uB1 = __float_as_uint(lgB1); uB1 = (uB1 & 0x80000000u) ? ~uB1 : (uB1 | 0x80000000u);
        unsigned long long kB0 = ((unsigned long long)uB0 << 32) | (0xFFFFFFFFu - (unsigned)vrB);
        unsigned long long kB1 = ((unsigned long long)uB1 << 32) | (0xFFFFFFFFu - (unsigned)vrB);
        bk0 = kB0 > bk0 ? kB0 : bk0;
        bk1 = kB1 > bk1 ? kB1 : bk1;
      }
      // combine the 4 rg groups (masks 16, 32 preserve kc)
#pragma unroll
      for (int m = 16; m <= 32; m <<= 1) {
        unsigned long long o0 = __shfl_xor(bk0, m, 64);
        unsigned long long o1 = __shfl_xor(bk1, m, 64);
        bk0 = o0 > bk0 ? o0 : bk0;
        bk1 = o1 > bk1 ? o1 : bk1;
      }
      if (rg == 0) {
        atomicMax(&amaxL[kc], bk0);
        atomicMax(&amaxL[kc + 16], bk1);
      }
    }
    __syncthreads();
    // coalesced logit writeback + global argmax merge
#pragma unroll
    for (int it = 0; it < 4; ++it) {
      int idx = tid + it * 1024;            // [0,4096)
      int b = idx >> 7, j = idx & 127;
      if (j < 125)
        out[((size_t)b * 64 + (t + 1)) * 32000 + bid * 125 + j] = oL[b * 130 + j];
    }
    if (tid < 32) atomicMax(&amax[t * 32 + tid], amaxL[tid]);
    gbar(flags, ++gen);
  }
}

extern "C" void kernel_launch(void* const* d_in, const int* in_sizes, int n_in,
                              void* d_out, int out_size, void* d_ws, size_t ws_size,
                              hipStream_t stream) {
  (void)in_sizes; (void)n_in; (void)out_size; (void)ws_size;
  const int*   src     = (const int*)d_in[0];
  const int*   tgt     = (const int*)d_in[1];
  const float* enc_emb = (const float*)d_in[2];
  const float* dec_emb = (const float*)d_in[3];
  const float* ewih_f  = (const float*)d_in[4];
  const float* ewhh_f  = (const float*)d_in[5];
  const float* ebih_f  = (const float*)d_in[6];
  const float* ebhh_f  = (const float*)d_in[7];
  const float* ewih_r  = (const float*)d_in[8];
  const float* ewhh_r  = (const float*)d_in[9];
  const float* ebih_r  = (const float*)d_in[10];
  const float* ebhh_r  = (const float*)d_in[11];
  const float* dwih_f  = (const float*)d_in[12];
  const float* dwhh_f  = (const float*)d_in[13];
  const float* dbih_f  = (const float*)d_in[14];
  const float* dbhh_f  = (const float*)d_in[15];
  const float* dwih_r  = (const float*)d_in[16];
  const float* dwhh_r  = (const float*)d_in[17];
  const float* dbih_r  = (const float*)d_in[18];
  const float* dbhh_r  = (const float*)d_in[19];
  const float* cls_w   = (const float*)d_in[20];
  const float* cls_b   = (const float*)d_in[21];

  char* ws = (char*)d_ws;
  unsigned long long* amax = (unsigned long long*)(ws + OFF_AMAX);
  unsigned* flags          = (unsigned*)(ws + OFF_FLAGS);
  float* Xg                = (float*)(ws + OFF_XG);
  float* h_enc             = (float*)(ws + OFF_HENC);
  float* hcat              = (float*)(ws + OFF_HCAT);

  // reset barrier flags + argmax slots (ws is poisoned 0xAA once before timing)
  hipMemsetAsync(d_ws, 0, OFF_XG, stream);

  static bool attr_set = []() {
    hipFuncSetAttribute((const void*)s2s_kernel,
                        hipFuncAttributeMaxDynamicSharedMemorySize, LDS_BYTES);
    return true;
  }();
  (void)attr_set;
  hipFuncSetAttribute((const void*)s2s_kernel,
                      hipFuncAttributeMaxDynamicSharedMemorySize, LDS_BYTES);

  hipLaunchKernelGGL(s2s_kernel, dim3(NBLK), dim3(NT), LDS_BYTES, stream,
                     src, tgt, enc_emb, dec_emb,
                     ewih_f, ewhh_f, ebih_f, ebhh_f,
                     ewih_r, ewhh_r, ebih_r, ebhh_r,
                     dwih_f, dwhh_f, dbih_f, dbhh_f,
                     dwih_r, dwhh_r, dbih_r, dbhh_r,
                     cls_w, cls_b,
                     (float*)d_out, amax, flags, Xg, h_enc, hcat);
}

// Round 4
// 19106.680 us; speedup vs baseline: 1.8844x; 1.0095x over previous
//
#include <hip/hip_runtime.h>
#include <stdint.h>

// Seq2Seq (bi-LSTM encoder + greedy LSTM decoder), MI355X gfx950.
// v4: clamp waves/EU to stop the spill.
//   R3 post-mortem: VGPR_Count=64 (compiler aimed for 8 waves/SIMD; our
//   launch is 1 block/CU so that occupancy is useless) -> acc[64] spilled
//   to scratch: +6.4 GB fetch / +12 GB write vs expected. Fix:
//   amdgpu_waves_per_eu(4,4) gives the allocator the full 128-VGPR budget
//   for our 16-wave block (occupancy unchanged). Classifier structure from
//   v3 kept: lane-coalesced weight stream (rg=4 rows x kc=16 k-chunks),
//   row-major h in LDS, butterfly reduce + static select tree, LDS-staged
//   coalesced logit writeback.
//
// B=32 S=128 T=64 V=32000 E=512 H=512 (4H=2048 gates per cell)

#define NT 1024
#define NBLK 256

constexpr int HSTR = 580;    // enc h-stage LDS row stride (512 + pad, %32==4)
constexpr int XSTR = 1156;   // dec [x|h]-stage stride (1024 + pad, %32==4)
constexpr unsigned LDS_BYTES = 150528;

// workspace layout (bytes)
constexpr size_t OFF_AMAX  = 0;                     // 63*32 u64 = 16128
constexpr size_t OFF_FLAGS = 16128;                 // 256 u32  = 1024
constexpr size_t OFF_XG    = 17408;                 // 256*128*32*16 f32 = 67108864
constexpr size_t OFF_HENC  = OFF_XG + 67108864ULL;  // 2buf*2dir*32*512 f32 = 262144
constexpr size_t OFF_HCAT  = OFF_HENC + 262144ULL;  // 2buf*32*1024 f32 = 262144

__device__ __forceinline__ float sigm(float x) {
  if (x >= 0.f) return 1.f / (1.f + expf(-x));
  float e = expf(x);
  return e / (1.f + e);
}

__device__ __forceinline__ void fma4(const float4& w, const float4& h, float4& a) {
  a.x = fmaf(w.x, h.x, a.x);
  a.y = fmaf(w.y, h.y, a.y);
  a.z = fmaf(w.z, h.z, a.z);
  a.w = fmaf(w.w, h.w, a.w);
}

__device__ __forceinline__ float hsum4(const float4& a) {
  return (a.x + a.y) + (a.z + a.w);
}

__device__ __forceinline__ float dot4(const float4& w, const float4& h, float acc) {
  return fmaf(w.x, h.x, fmaf(w.y, h.y, fmaf(w.z, h.z, fmaf(w.w, h.w, acc))));
}

// device-scope flag barrier: 256 blocks, thread t<256 polls flags[t].
__device__ __forceinline__ void gbar(unsigned* flags, unsigned gen) {
  __syncthreads();
  if (threadIdx.x == 0) {
    __threadfence();
    __hip_atomic_store(&flags[blockIdx.x], gen, __ATOMIC_RELEASE,
                       __HIP_MEMORY_SCOPE_AGENT);
  }
  if (threadIdx.x < NBLK) {
    while (__hip_atomic_load(&flags[threadIdx.x], __ATOMIC_ACQUIRE,
                             __HIP_MEMORY_SCOPE_AGENT) < gen) {
      __builtin_amdgcn_s_sleep(2);
    }
  }
  __syncthreads();
}

__global__ __attribute__((amdgpu_waves_per_eu(4, 4))) __launch_bounds__(NT)
void s2s_kernel(
    const int* __restrict__ src, const int* __restrict__ tgt,
    const float* __restrict__ enc_emb, const float* __restrict__ dec_emb,
    const float* __restrict__ ewih_f, const float* __restrict__ ewhh_f,
    const float* __restrict__ ebih_f, const float* __restrict__ ebhh_f,
    const float* __restrict__ ewih_r, const float* __restrict__ ewhh_r,
    const float* __restrict__ ebih_r, const float* __restrict__ ebhh_r,
    const float* __restrict__ dwih_f, const float* __restrict__ dwhh_f,
    const float* __restrict__ dbih_f, const float* __restrict__ dbhh_f,
    const float* __restrict__ dwih_r, const float* __restrict__ dwhh_r,
    const float* __restrict__ dbih_r, const float* __restrict__ dbhh_r,
    const float* __restrict__ cls_w, const float* __restrict__ cls_b,
    float* __restrict__ out,
    unsigned long long* __restrict__ amax, unsigned* __restrict__ flags,
    float* __restrict__ Xg, float* __restrict__ h_enc, float* __restrict__ hcat) {
  extern __shared__ float smem[];
  const int tid = threadIdx.x;
  const int bid = blockIdx.x;
  const int d  = bid >> 7;          // 0 = forward, 1 = reverse
  const int u0 = (bid & 127) << 2;  // first of 4 owned LSTM units

  // LDS views per phase (aliased)
  float* hL  = smem;                      // enc: [32][HSTR]
  float* XgL = smem + 32 * HSTR;          // enc: [32*16]
  float* gL  = XgL + 512;                 // enc: [32*16]
  float* xhL = smem;                      // dec cell: [32][XSTR]
  float* gLd = smem + 32 * XSTR;          // dec cell: [32*16]  (floats 36992..37504)
  // classifier phase: cH float4[8192] at floats 0..32768 (128 KB)
  //                   oL [32][130] at floats 32768..36928
  //                   amaxL u64[32] at floats 37504..37568
  float* oL = smem + 32768;
  unsigned long long* amaxL = (unsigned long long*)(smem + 37504);

  // mapping E (phase0 + encoder scan): 2 rows x 4 b per thread, k-split 16
  const int rgE = tid >> 7;               // [0,8)
  const int bpE = (tid >> 4) & 7;         // [0,8)
  const int ksE = tid & 15;               // [0,16)
  const int r0E = rgE * 2, r1E = r0E + 1;
  const int growE0 = (r0E & 3) * 512 + u0 + (r0E >> 2);
  const int growE1 = (r1E & 3) * 512 + u0 + (r1E >> 2);
  // mapping D (decoder cells): 2 rows x 8 b per thread, k-split 32 over K=1024
  const int rgD = tid >> 7;
  const int bpD = (tid >> 5) & 3;         // [0,4)
  const int ksD = tid & 31;               // [0,32)
  const int r0D = rgD * 2, r1D = r0D + 1;
  const int growD0 = (r0D & 3) * 512 + u0 + (r0D >> 2);
  const int growD1 = (r1D & 3) * 512 + u0 + (r1D >> 2);

  const float* ewih = d ? ewih_r : ewih_f;
  const float* ewhh = d ? ewhh_r : ewhh_f;
  const float* ebih = d ? ebih_r : ebih_f;
  const float* ebhh = d ? ebhh_r : ebhh_f;
  const float* dwih = d ? dwih_r : dwih_f;
  const float* dwhh = d ? dwhh_r : dwhh_f;
  const float* dbih = d ? dbih_r : dbih_f;
  const float* dbhh = d ? dbhh_r : dbhh_f;

  float4 wA[8], wB[8];
  float biasA, biasB;
  float c_reg = 0.f;   // cell state for threads tid<128 (b=tid&31, j=tid>>5)
  unsigned gen = 0;

  // ---------------- phase 0: Xg = emb(src) @ wih^T + bih + bhh ----------------
#pragma unroll
  for (int i4 = 0; i4 < 8; ++i4) {
    wA[i4] = *(const float4*)(ewih + (size_t)growE0 * 512 + ksE * 32 + i4 * 4);
    wB[i4] = *(const float4*)(ewih + (size_t)growE1 * 512 + ksE * 32 + i4 * 4);
  }
  biasA = ebih[growE0] + ebhh[growE0];
  biasB = ebih[growE1] + ebhh[growE1];

  for (int t = 0; t < 128; ++t) {
    {  // stage x = enc_emb[src[b][t]] into hL
      int b = tid >> 5, i = tid & 31;
      int tok = src[b * 128 + t];
      const float* row = enc_emb + (size_t)tok * 512;
#pragma unroll
      for (int q = 0; q < 4; ++q) {
        int k = (i + 32 * q) * 4;
        float4 v = *(const float4*)(row + k);
        int pc = k + ((k >> 5) << 2);
        *(float4*)(hL + b * HSTR + pc) = v;
      }
    }
    __syncthreads();
    for (int gi = 0; gi < 4; ++gi) {
      int b = bpE * 4 + gi;
      const float* hb = hL + b * HSTR + ksE * 36;
      float4 a0 = {0, 0, 0, 0}, a1 = {0, 0, 0, 0};
#pragma unroll
      for (int i4 = 0; i4 < 8; ++i4) {
        float4 h4 = *(const float4*)(hb + i4 * 4);
        fma4(wA[i4], h4, a0);
        fma4(wB[i4], h4, a1);
      }
      float s0 = hsum4(a0), s1 = hsum4(a1);
#pragma unroll
      for (int m = 1; m <= 8; m <<= 1) {
        s0 += __shfl_xor(s0, m, 64);
        s1 += __shfl_xor(s1, m, 64);
      }
      if (ksE == 0) {
        float* xgp = Xg + ((size_t)bid << 16) + t * 512 + b * 16;
        xgp[r0E] = s0 + biasA;
        xgp[r1E] = s1 + biasB;
      }
    }
    __syncthreads();
  }

  // init h_enc[buf0] = 0 for owned units; zero out[:,0,:] slice
  if (tid < 128) {
    int b = tid & 31, j = tid >> 5;
    h_enc[((0 * 2 + d) * 32 + b) * 512 + u0 + j] = 0.f;
  }
  for (int i = tid; i < 4000; i += NT) {
    int b = i & 31, vv = i >> 5;  // vv < 125
    out[(size_t)b * 64 * 32000 + bid * 125 + vv] = 0.f;
  }
  gbar(flags, ++gen);

  // ---------------- encoder scan: 128 steps ----------------
#pragma unroll
  for (int i4 = 0; i4 < 8; ++i4) {
    wA[i4] = *(const float4*)(ewhh + (size_t)growE0 * 512 + ksE * 32 + i4 * 4);
    wB[i4] = *(const float4*)(ewhh + (size_t)growE1 * 512 + ksE * 32 + i4 * 4);
  }
  int cur = 0;
  for (int s = 0; s < 128; ++s) {
    const int td = d ? (127 - s) : s;
    {  // stage h_enc[cur][d] -> hL; stage this block's Xg slice -> XgL
      int b = tid >> 5, i = tid & 31;
      const float* hr = h_enc + ((size_t)(cur * 2 + d) * 32 + b) * 512;
#pragma unroll
      for (int q = 0; q < 4; ++q) {
        int k = (i + 32 * q) * 4;
        float4 v = *(const float4*)(hr + k);
        int pc = k + ((k >> 5) << 2);
        *(float4*)(hL + b * HSTR + pc) = v;
      }
      if (tid < 128) {
        ((float4*)XgL)[tid] =
            *(const float4*)(Xg + ((size_t)bid << 16) + td * 512 + tid * 4);
      }
    }
    __syncthreads();
    for (int gi = 0; gi < 4; ++gi) {
      int b = bpE * 4 + gi;
      const float* hb = hL + b * HSTR + ksE * 36;
      float4 a0 = {0, 0, 0, 0}, a1 = {0, 0, 0, 0};
#pragma unroll
      for (int i4 = 0; i4 < 8; ++i4) {
        float4 h4 = *(const float4*)(hb + i4 * 4);
        fma4(wA[i4], h4, a0);
        fma4(wB[i4], h4, a1);
      }
      float s0 = hsum4(a0), s1 = hsum4(a1);
#pragma unroll
      for (int m = 1; m <= 8; m <<= 1) {
        s0 += __shfl_xor(s0, m, 64);
        s1 += __shfl_xor(s1, m, 64);
      }
      if (ksE == 0) {
        gL[b * 16 + r0E] = s0 + XgL[b * 16 + r0E];
        gL[b * 16 + r1E] = s1 + XgL[b * 16 + r1E];
      }
    }
    __syncthreads();
    if (tid < 128) {
      int b = tid & 31, j = tid >> 5;
      float g_i = gL[b * 16 + (j << 2) + 0];
      float g_f = gL[b * 16 + (j << 2) + 1];
      float g_g = gL[b * 16 + (j << 2) + 2];
      float g_o = gL[b * 16 + (j << 2) + 3];
      c_reg = sigm(g_f) * c_reg + sigm(g_i) * tanhf(g_g);
      float h = sigm(g_o) * tanhf(c_reg);
      h_enc[(((cur ^ 1) * 2 + d) * 32 + b) * 512 + u0 + j] = h;
      if (s == 127) hcat[b * 1024 + d * 512 + u0 + j] = h;  // buf 0
    }
    gbar(flags, ++gen);
    cur ^= 1;
  }

  // ---------------- decoder: 63 steps ----------------
  for (int t = 0; t < 63; ++t) {
    const int p = t & 1;
    {  // stage [x | h_d] into xhL
      int b = tid >> 5, i = tid & 31;
      int tok;
      if (t == 0) {
        tok = tgt[b * 64];
      } else {
        unsigned long long kv = amax[(t - 1) * 32 + b];
        tok = (int)(0xFFFFFFFFu - (unsigned)(kv & 0xFFFFFFFFull));
      }
      const float* xr = dec_emb + (size_t)tok * 512;
      const float* hr = hcat + (size_t)p * 32768 + b * 1024 + d * 512;
#pragma unroll
      for (int q = 0; q < 4; ++q) {
        int k = (i + 32 * q) * 4;
        float4 v = *(const float4*)(xr + k);
        int pc = k + ((k >> 5) << 2);
        *(float4*)(xhL + b * XSTR + pc) = v;
      }
#pragma unroll
      for (int q = 0; q < 4; ++q) {
        int k = (i + 32 * q) * 4;
        float4 v = *(const float4*)(hr + k);
        int c2 = 512 + k;
        int pc = c2 + ((c2 >> 5) << 2);
        *(float4*)(xhL + b * XSTR + pc) = v;
      }
    }
    // reload decoder cell weights each step (frees VGPR for classifier)
    {
      const float* s0p = (ksD < 16) ? (dwih + (size_t)growD0 * 512 + ksD * 32)
                                    : (dwhh + (size_t)growD0 * 512 + (ksD - 16) * 32);
      const float* s1p = (ksD < 16) ? (dwih + (size_t)growD1 * 512 + ksD * 32)
                                    : (dwhh + (size_t)growD1 * 512 + (ksD - 16) * 32);
#pragma unroll
      for (int i4 = 0; i4 < 8; ++i4) {
        wA[i4] = *(const float4*)(s0p + i4 * 4);
        wB[i4] = *(const float4*)(s1p + i4 * 4);
      }
      biasA = dbih[growD0] + dbhh[growD0];
      biasB = dbih[growD1] + dbhh[growD1];
    }
    __syncthreads();
    for (int gi = 0; gi < 8; ++gi) {
      int b = bpD * 8 + gi;
      const float* hb = xhL + b * XSTR + ksD * 36;
      float4 a0 = {0, 0, 0, 0}, a1 = {0, 0, 0, 0};
#pragma unroll
      for (int i4 = 0; i4 < 8; ++i4) {
        float4 h4 = *(const float4*)(hb + i4 * 4);
        fma4(wA[i4], h4, a0);
        fma4(wB[i4], h4, a1);
      }
      float s0 = hsum4(a0), s1 = hsum4(a1);
#pragma unroll
      for (int m = 1; m <= 16; m <<= 1) {
        s0 += __shfl_xor(s0, m, 64);
        s1 += __shfl_xor(s1, m, 64);
      }
      if (ksD == 0) {
        gLd[b * 16 + r0D] = s0 + biasA;
        gLd[b * 16 + r1D] = s1 + biasB;
      }
    }
    __syncthreads();
    if (tid < 128) {
      int b = tid & 31, j = tid >> 5;
      float g_i = gLd[b * 16 + (j << 2) + 0];
      float g_f = gLd[b * 16 + (j << 2) + 1];
      float g_g = gLd[b * 16 + (j << 2) + 2];
      float g_o = gLd[b * 16 + (j << 2) + 3];
      c_reg = sigm(g_f) * c_reg + sigm(g_i) * tanhf(g_g);
      float h = sigm(g_o) * tanhf(c_reg);
      hcat[(size_t)(p ^ 1) * 32768 + b * 1024 + d * 512 + u0 + j] = h;
    }
    gbar(flags, ++gen);

    // ---- classifier: logits = h @ cls_w^T + cls_b, argmax ----
    {  // stage h (plain row-major [32][1024]) into cH; zero amaxL
      const float* hr = hcat + (size_t)(p ^ 1) * 32768;
      float4* cH = (float4*)smem;
#pragma unroll
      for (int q = 0; q < 8; ++q) {
        int f = tid + q * 1024;
        cH[f] = *(const float4*)(hr + f * 4);
      }
      if (tid < 32) amaxL[tid] = 0ull;
    }
    __syncthreads();
    {
      const int wid = tid >> 6, lane = tid & 63;
      const int rg = lane >> 4;   // [0,4): this lane owns rows rg and rg+4
      const int kc = lane & 15;   // k-chunk within row
      const float4* cH = (const float4*)smem;
      const int lrA = wid * 8 + rg;        // 0..123, always valid
      const int lrB = lrA + 4;             // up to 127; rows >=125 invalid
      const int lrBc = lrB > 124 ? 124 : lrB;
      const int vrA = bid * 125 + lrA;
      const int vrB = bid * 125 + lrBc;
      const float4* wpA = (const float4*)(cls_w + (size_t)vrA * 1024) + kc;
      const float4* wpB = (const float4*)(cls_w + (size_t)vrB * 1024) + kc;
      float accA[32], accB[32];
#pragma unroll
      for (int b = 0; b < 32; ++b) { accA[b] = 0.f; accB[b] = 0.f; }
      float4 wa = wpA[0], wb = wpB[0];
      for (int q = 0; q < 16; ++q) {
        const int qn = (q + 1) & 15;
        float4 wan = wpA[qn * 16];   // prefetch next k-chunk (coalesced 256B/row-group)
        float4 wbn = wpB[qn * 16];
        const float4* hp0 = cH + q * 16 + kc;
#pragma unroll
        for (int b = 0; b < 32; ++b) {
          const float4* hb = (b < 16) ? hp0 : (hp0 + 4096);
          float4 h4 = hb[(b & 15) * 256];
          accA[b] = dot4(wa, h4, accA[b]);
          accB[b] = dot4(wb, h4, accB[b]);
        }
        wa = wan; wb = wbn;
      }
      // butterfly-sum over the 16 kc lanes (masks 1,2,4,8)
#pragma unroll
      for (int b = 0; b < 32; ++b) {
#pragma unroll
        for (int m = 1; m <= 8; m <<= 1) {
          accA[b] += __shfl_xor(accA[b], m, 64);
          accB[b] += __shfl_xor(accB[b], m, 64);
        }
      }
      // static select tree: this lane keeps b0=kc, b1=kc+16
      float a0[8], a1[8], b0v[8], b1v[8];
#pragma unroll
      for (int i = 0; i < 8; ++i) {
        a0[i]  = (kc & 8) ? accA[i + 8]  : accA[i];
        a1[i]  = (kc & 8) ? accA[i + 24] : accA[i + 16];
        b0v[i] = (kc & 8) ? accB[i + 8]  : accB[i];
        b1v[i] = (kc & 8) ? accB[i + 24] : accB[i + 16];
      }
#pragma unroll
      for (int i = 0; i < 4; ++i) {
        a0[i]  = (kc & 4) ? a0[i + 4]  : a0[i];
        a1[i]  = (kc & 4) ? a1[i + 4]  : a1[i];
        b0v[i] = (kc & 4) ? b0v[i + 4] : b0v[i];
        b1v[i] = (kc & 4) ? b1v[i + 4] : b1v[i];
      }
#pragma unroll
      for (int i = 0; i < 2; ++i) {
        a0[i]  = (kc & 2) ? a0[i + 2]  : a0[i];
        a1[i]  = (kc & 2) ? a1[i + 2]  : a1[i];
        b0v[i] = (kc & 2) ? b0v[i + 2] : b0v[i];
        b1v[i] = (kc & 2) ? b1v[i + 2] : b1v[i];
      }
      a0[0]  = (kc & 1) ? a0[1]  : a0[0];
      a1[0]  = (kc & 1) ? a1[1]  : a1[0];
      b0v[0] = (kc & 1) ? b0v[1] : b0v[0];
      b1v[0] = (kc & 1) ? b1v[1] : b1v[0];

      const float cbA = cls_b[vrA], cbB = cls_b[vrB];
      const float lgA0 = a0[0] + cbA;   // (row lrA, b=kc)
      const float lgA1 = a1[0] + cbA;   // (row lrA, b=kc+16)
      const float lgB0 = b0v[0] + cbB;  // (row lrB, b=kc)
      const float lgB1 = b1v[0] + cbB;  // (row lrB, b=kc+16)

      // stage into oL[b][row_local] (stride 130 -> conflict-free) for coalesced writeback
      oL[kc * 130 + lrA] = lgA0;
      oL[(kc + 16) * 130 + lrA] = lgA1;
      oL[kc * 130 + lrB] = lgB0;        // rows 125..127 staged but filtered later
      oL[(kc + 16) * 130 + lrB] = lgB1;

      // argmax keys (ordered-float <<32 | ~vrow  => max = first-index-wins argmax)
      unsigned uA0 = __float_as_uint(lgA0); uA0 = (uA0 & 0x80000000u) ? ~uA0 : (uA0 | 0x80000000u);
      unsigned uA1 = __float_as_uint(lgA1); uA1 = (uA1 & 0x80000000u) ? ~uA1 : (uA1 | 0x80000000u);
      unsigned long long bk0 = ((unsigned long long)uA0 << 32) | (0xFFFFFFFFu - (unsigned)vrA);
      unsigned long long bk1 = ((unsigned long long)uA1 << 32) | (0xFFFFFFFFu - (unsigned)vrA);
      if (lrB < 125) {
        unsigned uB0 = __float_as_uint(lgB0); uB0 = (uB0 & 0x80000000u) ? ~uB0 : (uB0 | 0x80000000u);
        unsigned uB1 = __float_as_uint(lgB1); uB1 = (uB1 & 0x80000000u) ? ~uB1 : (uB1 | 0x80000000u);
        unsigned long long kB0 = ((unsigned long long)uB0 << 32) | (0xFFFFFFFFu - (unsigned)vrB);
        unsigned long long kB1 = ((unsigned long long)uB1 << 32) | (0xFFFFFFFFu - (unsigned)vrB);
        bk0 = kB0 > bk0 ? kB0 : bk0;
        bk1 = kB1 > bk1 ? kB1 : bk1;
      }
      // combine the 4 rg groups (masks 16, 32 preserve kc)
#pragma unroll
      for (int m = 16; m <= 32; m <<= 1) {
        unsigned long long o0 = __shfl_xor(bk0, m, 64);
        unsigned long long o1 = __shfl_xor(bk1, m, 64);
        bk0 = o0 > bk0 ? o0 : bk0;
        bk1 = o1 > bk1 ? o1 : bk1;
      }
      if (rg == 0) {
        atomicMax(&amaxL[kc], bk0);
        atomicMax(&amaxL[kc + 16], bk1);
      }
    }
    __syncthreads();
    // coalesced logit writeback + global argmax merge
#pragma unroll
    for (int it = 0; it < 4; ++it) {
      int idx = tid + it * 1024;            // [0,4096)
      int b = idx >> 7, j = idx & 127;
      if (j < 125)
        out[((size_t)b * 64 + (t + 1)) * 32000 + bid * 125 + j] = oL[b * 130 + j];
    }
    if (tid < 32) atomicMax(&amax[t * 32 + tid], amaxL[tid]);
    gbar(flags, ++gen);
  }
}

extern "C" void kernel_launch(void* const* d_in, const int* in_sizes, int n_in,
                              void* d_out, int out_size, void* d_ws, size_t ws_size,
                              hipStream_t stream) {
  (void)in_sizes; (void)n_in; (void)out_size; (void)ws_size;
  const int*   src     = (const int*)d_in[0];
  const int*   tgt     = (const int*)d_in[1];
  const float* enc_emb = (const float*)d_in[2];
  const float* dec_emb = (const float*)d_in[3];
  const float* ewih_f  = (const float*)d_in[4];
  const float* ewhh_f  = (const float*)d_in[5];
  const float* ebih_f  = (const float*)d_in[6];
  const float* ebhh_f  = (const float*)d_in[7];
  const float* ewih_r  = (const float*)d_in[8];
  const float* ewhh_r  = (const float*)d_in[9];
  const float* ebih_r  = (const float*)d_in[10];
  const float* ebhh_r  = (const float*)d_in[11];
  const float* dwih_f  = (const float*)d_in[12];
  const float* dwhh_f  = (const float*)d_in[13];
  const float* dbih_f  = (const float*)d_in[14];
  const float* dbhh_f  = (const float*)d_in[15];
  const float* dwih_r  = (const float*)d_in[16];
  const float* dwhh_r  = (const float*)d_in[17];
  const float* dbih_r  = (const float*)d_in[18];
  const float* dbhh_r  = (const float*)d_in[19];
  const float* cls_w   = (const float*)d_in[20];
  const float* cls_b   = (const float*)d_in[21];

  char* ws = (char*)d_ws;
  unsigned long long* amax = (unsigned long long*)(ws + OFF_AMAX);
  unsigned* flags          = (unsigned*)(ws + OFF_FLAGS);
  float* Xg                = (float*)(ws + OFF_XG);
  float* h_enc             = (float*)(ws + OFF_HENC);
  float* hcat              = (float*)(ws + OFF_HCAT);

  // reset barrier flags + argmax slots (ws is poisoned 0xAA once before timing)
  hipMemsetAsync(d_ws, 0, OFF_XG, stream);

  static bool attr_set = []() {
    hipFuncSetAttribute((const void*)s2s_kernel,
                        hipFuncAttributeMaxDynamicSharedMemorySize, LDS_BYTES);
    return true;
  }();
  (void)attr_set;
  hipFuncSetAttribute((const void*)s2s_kernel,
                      hipFuncAttributeMaxDynamicSharedMemorySize, LDS_BYTES);

  hipLaunchKernelGGL(s2s_kernel, dim3(NBLK), dim3(NT), LDS_BYTES, stream,
                     src, tgt, enc_emb, dec_emb,
                     ewih_f, ewhh_f, ebih_f, ebhh_f,
                     ewih_r, ewhh_r, ebih_r, ebhh_r,
                     dwih_f, dwhh_f, dbih_f, dbhh_f,
                     dwih_r, dwhh_r, dbih_r, dbhh_r,
                     cls_w, cls_b,
                     (float*)d_out, amax, flags, Xg, h_enc, hcat);
}